// Round 2
// baseline (72.482 us; speedup 1.0000x reference)
//
#include <hip/hip_runtime.h>

#define N_SLOTS 65536
#define DIM 128
#define B_SZ 4096
#define K_TOP 8
#define UPDATE_RATE 0.1f
#define MOMENTUM 0.9f
#define GATE_THRESH 0.01f

typedef float f32x4 __attribute__((ext_vector_type(4)));

// ---------------------------------------------------------------------------
// Kernel 1: scatter-add gate weights into per-slot counts (ws, 65536 floats).
// ---------------------------------------------------------------------------
__global__ void mw_counts_kernel(const float* __restrict__ gate,
                                 const int* __restrict__ top_idx,
                                 float* __restrict__ counts) {
    int t = blockIdx.x * blockDim.x + threadIdx.x;
    if (t >= B_SZ * K_TOP) return;
    int a = t >> 3;                       // t / K_TOP
    float g = gate[a];
    float w = (g > GATE_THRESH) ? g * UPDATE_RATE : 0.0f;
    if (w != 0.0f) {
        atomicAdd(&counts[top_idx[t]], w);
    }
}

// ---------------------------------------------------------------------------
// Kernel 2: out = memory + MOMENTUM * momentum (keys and values).
// Grid-stride for ILP; non-temporal stores so the 64 MB output (write-once,
// never re-read this replay) doesn't evict the L3-resident inputs.
// ---------------------------------------------------------------------------
__global__ void __launch_bounds__(256) mw_base_kernel(
        const f32x4* __restrict__ mk,
        const f32x4* __restrict__ mv,
        const f32x4* __restrict__ km,
        const f32x4* __restrict__ vm,
        f32x4* __restrict__ outk,
        f32x4* __restrict__ outv,
        int n4) {
    int stride = gridDim.x * blockDim.x;
    for (int i = blockIdx.x * blockDim.x + threadIdx.x; i < n4; i += stride) {
        // issue all four loads before any use
        f32x4 a0 = mk[i];
        f32x4 b0 = km[i];
        f32x4 a1 = mv[i];
        f32x4 b1 = vm[i];
        f32x4 r0 = a0 + MOMENTUM * b0;
        f32x4 r1 = a1 + MOMENTUM * b1;
        __builtin_nontemporal_store(r0, &outk[i]);
        __builtin_nontemporal_store(r1, &outv[i]);
    }
}

// ---------------------------------------------------------------------------
// Kernel 3: scatter normalized updates. One block per write `a`:
// lanes 0..127 own the key row, 128..255 the value row; k-loop inside so
// q/v are loaded once per block instead of once per (a,k) pair.
// ---------------------------------------------------------------------------
__global__ void __launch_bounds__(256) mw_scatter_kernel(
        const float* __restrict__ q,
        const float* __restrict__ v,
        const float* __restrict__ gate,
        const int* __restrict__ top_idx,
        const float* __restrict__ counts,
        float* __restrict__ outk,
        float* __restrict__ outv) {
    int a = blockIdx.x;                   // 0 .. B-1
    float g = gate[a];
    float w = (g > GATE_THRESH) ? g * UPDATE_RATE : 0.0f;
    if (w == 0.0f) return;                // block-uniform exit
    int t = threadIdx.x;
    int d = t & (DIM - 1);
    bool is_key = (t < DIM);
    float x = is_key ? q[a * DIM + d] : v[a * DIM + d];
    float* base = is_key ? outk : outv;
    float wm = (1.0f - MOMENTUM) * w;
#pragma unroll
    for (int k = 0; k < K_TOP; ++k) {
        int s = top_idx[a * K_TOP + k];
        float cnt = counts[s];
        float denom = (cnt > 0.0f) ? cnt : 1.0f;
        float c = wm / denom;
        atomicAdd(&base[s * DIM + d], c * x);
    }
}

extern "C" void kernel_launch(void* const* d_in, const int* in_sizes, int n_in,
                              void* d_out, int out_size, void* d_ws, size_t ws_size,
                              hipStream_t stream) {
    const float* memory_keys    = (const float*)d_in[0];
    const float* memory_values  = (const float*)d_in[1];
    const float* write_query    = (const float*)d_in[2];
    const float* write_value    = (const float*)d_in[3];
    const float* gate_weights   = (const float*)d_in[4];
    const int*   top_indices    = (const int*)d_in[5];
    const float* key_momentum   = (const float*)d_in[6];
    const float* value_momentum = (const float*)d_in[7];

    float* out  = (float*)d_out;
    float* outk = out;
    float* outv = out + (size_t)N_SLOTS * DIM;

    float* counts = (float*)d_ws;         // 65536 floats = 256 KB

    // 0) zero the counts accumulator (deterministic per call)
    hipMemsetAsync(counts, 0, N_SLOTS * sizeof(float), stream);

    // 1) accumulate per-slot gate-weight counts
    {
        int total = B_SZ * K_TOP;         // 32768
        int block = 256;
        int grid = (total + block - 1) / block;
        mw_counts_kernel<<<grid, block, 0, stream>>>(gate_weights, top_indices, counts);
    }

    // 2) out = memory + 0.9 * momentum  (streaming, float4, grid-stride)
    {
        int n4 = N_SLOTS * DIM / 4;       // 2,097,152
        int block = 256;
        int grid = 2048;                  // 4 iterations per thread
        mw_base_kernel<<<grid, block, 0, stream>>>(
            (const f32x4*)memory_keys, (const f32x4*)memory_values,
            (const f32x4*)key_momentum, (const f32x4*)value_momentum,
            (f32x4*)outk, (f32x4*)outv, n4);
    }

    // 3) scatter normalized updates into the output
    {
        mw_scatter_kernel<<<B_SZ, 256, 0, stream>>>(
            write_query, write_value, gate_weights, top_indices, counts,
            outk, outv);
    }
}

// Round 3
// 67.464 us; speedup vs baseline: 1.0744x; 1.0744x over previous
//
#include <hip/hip_runtime.h>

#define N_SLOTS 65536
#define DIM 128
#define B_SZ 4096
#define K_TOP 8
#define UPDATE_RATE 0.1f
#define MOMENTUM 0.9f
#define GATE_THRESH 0.01f

typedef float f32x4 __attribute__((ext_vector_type(4)));

// ---------------------------------------------------------------------------
// Kernel 1 (fused into base): out = memory + MOMENTUM * momentum, plus the
// counts scatter-add done by the first 32768 threads (grid is 2048x256; the
// first 128 blocks cover all B*K pairs). Kernel-end barrier guarantees counts
// are final before the scatter kernel reads them.
//
// Streaming layout: one-shot grid; each block owns a contiguous chunk of
// 1024 float4 per stream; thread t handles chunk+t, +256, +512, +768 so every
// load instruction is fully wave-coalesced (64 lanes x 16B = 1KB/line-run).
// 8 loads in flight per half (keys, then values) to maximize MLP while
// keeping VGPRs moderate.
// ---------------------------------------------------------------------------
__global__ void __launch_bounds__(256) mw_base_kernel(
        const f32x4* __restrict__ mk,
        const f32x4* __restrict__ mv,
        const f32x4* __restrict__ km,
        const f32x4* __restrict__ vm,
        f32x4* __restrict__ outk,
        f32x4* __restrict__ outv,
        const float* __restrict__ gate,
        const int* __restrict__ top_idx,
        float* __restrict__ counts) {
    // --- fused counts scatter (first 32768 threads) ---
    int gtid = blockIdx.x * blockDim.x + threadIdx.x;
    if (gtid < B_SZ * K_TOP) {
        int a = gtid >> 3;
        float g = gate[a];
        float w = (g > GATE_THRESH) ? g * UPDATE_RATE : 0.0f;
        if (w != 0.0f) {
            atomicAdd(&counts[top_idx[gtid]], w);
        }
    }

    // --- streaming base: 4 float4 per thread per stream, lane-contiguous ---
    int base = blockIdx.x * 1024 + threadIdx.x;

    // keys half: 8 loads hoisted, then 4 stores
    f32x4 a0 = mk[base];
    f32x4 a1 = mk[base + 256];
    f32x4 a2 = mk[base + 512];
    f32x4 a3 = mk[base + 768];
    f32x4 b0 = km[base];
    f32x4 b1 = km[base + 256];
    f32x4 b2 = km[base + 512];
    f32x4 b3 = km[base + 768];
    outk[base]       = a0 + MOMENTUM * b0;
    outk[base + 256] = a1 + MOMENTUM * b1;
    outk[base + 512] = a2 + MOMENTUM * b2;
    outk[base + 768] = a3 + MOMENTUM * b3;

    // values half
    a0 = mv[base];
    a1 = mv[base + 256];
    a2 = mv[base + 512];
    a3 = mv[base + 768];
    b0 = vm[base];
    b1 = vm[base + 256];
    b2 = vm[base + 512];
    b3 = vm[base + 768];
    outv[base]       = a0 + MOMENTUM * b0;
    outv[base + 256] = a1 + MOMENTUM * b1;
    outv[base + 512] = a2 + MOMENTUM * b2;
    outv[base + 768] = a3 + MOMENTUM * b3;
}

// ---------------------------------------------------------------------------
// Kernel 2: scatter normalized updates. One block per write `a`:
// lanes 0..127 own the key row, 128..255 the value row; k-loop inside so
// q/v are loaded once per block instead of once per (a,k) pair.
// ---------------------------------------------------------------------------
__global__ void __launch_bounds__(256) mw_scatter_kernel(
        const float* __restrict__ q,
        const float* __restrict__ v,
        const float* __restrict__ gate,
        const int* __restrict__ top_idx,
        const float* __restrict__ counts,
        float* __restrict__ outk,
        float* __restrict__ outv) {
    int a = blockIdx.x;                   // 0 .. B-1
    float g = gate[a];
    float w = (g > GATE_THRESH) ? g * UPDATE_RATE : 0.0f;
    if (w == 0.0f) return;                // block-uniform exit
    int t = threadIdx.x;
    int d = t & (DIM - 1);
    bool is_key = (t < DIM);
    float x = is_key ? q[a * DIM + d] : v[a * DIM + d];
    float* base = is_key ? outk : outv;
    float wm = (1.0f - MOMENTUM) * w;
#pragma unroll
    for (int k = 0; k < K_TOP; ++k) {
        int s = top_idx[a * K_TOP + k];
        float cnt = counts[s];
        float denom = (cnt > 0.0f) ? cnt : 1.0f;
        float c = wm / denom;
        atomicAdd(&base[s * DIM + d], c * x);
    }
}

extern "C" void kernel_launch(void* const* d_in, const int* in_sizes, int n_in,
                              void* d_out, int out_size, void* d_ws, size_t ws_size,
                              hipStream_t stream) {
    const float* memory_keys    = (const float*)d_in[0];
    const float* memory_values  = (const float*)d_in[1];
    const float* write_query    = (const float*)d_in[2];
    const float* write_value    = (const float*)d_in[3];
    const float* gate_weights   = (const float*)d_in[4];
    const int*   top_indices    = (const int*)d_in[5];
    const float* key_momentum   = (const float*)d_in[6];
    const float* value_momentum = (const float*)d_in[7];

    float* out  = (float*)d_out;
    float* outk = out;
    float* outv = out + (size_t)N_SLOTS * DIM;

    float* counts = (float*)d_ws;         // 65536 floats = 256 KB

    // 0) zero the counts accumulator (deterministic per call)
    hipMemsetAsync(counts, 0, N_SLOTS * sizeof(float), stream);

    // 1) fused: streaming base pass + counts scatter
    {
        int grid = N_SLOTS * DIM / 4 / 1024;   // 2048 blocks, one-shot
        mw_base_kernel<<<grid, 256, 0, stream>>>(
            (const f32x4*)memory_keys, (const f32x4*)memory_values,
            (const f32x4*)key_momentum, (const f32x4*)value_momentum,
            (f32x4*)outk, (f32x4*)outv,
            gate_weights, top_indices, counts);
    }

    // 2) scatter normalized updates into the output
    {
        mw_scatter_kernel<<<B_SZ, 256, 0, stream>>>(
            write_query, write_value, gate_weights, top_indices, counts,
            outk, outv);
    }
}

// Round 4
// 66.610 us; speedup vs baseline: 1.0882x; 1.0128x over previous
//
#include <hip/hip_runtime.h>

#define N_SLOTS 65536
#define DIM 128
#define B_SZ 4096
#define K_TOP 8
#define UPDATE_RATE 0.1f
#define MOMENTUM 0.9f
#define GATE_THRESH 0.01f

typedef float f32x4 __attribute__((ext_vector_type(4)));

// ---------------------------------------------------------------------------
// Base pass: out = memory + MOMENTUM * momentum.
//   - Halved by BLOCK: blocks [0,4096) process keys, [4096,8192) values, so
//     each wave touches only 3 streams (mem, mom, out) instead of 6.
//   - XCD-contiguous swizzle: block->XCD is round-robin (bid%8); remap so
//     all blocks on one XCD cover a contiguous 4 MB region of each buffer
//     (DRAM page locality + disjoint per-XCD L2 footprints).
//   - 2 f32x4 per thread (8 KB per block), lane-contiguous.
//   - Counts scatter-add fused into the first 128 blocks (gtid < B*K);
//     kernel-end barrier orders it before the scatter kernel reads counts.
// ---------------------------------------------------------------------------
__global__ void __launch_bounds__(256) mw_base_kernel(
        const f32x4* __restrict__ mk,
        const f32x4* __restrict__ mv,
        const f32x4* __restrict__ km,
        const f32x4* __restrict__ vm,
        f32x4* __restrict__ outk,
        f32x4* __restrict__ outv,
        const float* __restrict__ gate,
        const int* __restrict__ top_idx,
        float* __restrict__ counts) {
    int bid = blockIdx.x;
    int gtid = bid * 256 + threadIdx.x;

    // --- fused counts scatter (first 128 blocks) ---
    if (gtid < B_SZ * K_TOP) {
        int a = gtid >> 3;
        float g = gate[a];
        float w = (g > GATE_THRESH) ? g * UPDATE_RATE : 0.0f;
        if (w != 0.0f) {
            atomicAdd(&counts[top_idx[gtid]], w);
        }
    }

    // --- streaming half: 3 streams per wave ---
    int half = bid >> 12;                 // 0 = keys, 1 = values
    int blk  = bid & 4095;
    // XCD-contiguous: XCD j (= bid%8) covers blocks [j*512, (j+1)*512)
    int swz  = (blk & 7) * 512 + (blk >> 3);

    const f32x4* __restrict__ mem = half ? mv : mk;
    const f32x4* __restrict__ mom = half ? vm : km;
    f32x4* __restrict__ out       = half ? outv : outk;

    int base = swz * 512 + threadIdx.x;
    f32x4 a0 = mem[base];
    f32x4 a1 = mem[base + 256];
    f32x4 b0 = mom[base];
    f32x4 b1 = mom[base + 256];
    out[base]       = a0 + MOMENTUM * b0;
    out[base + 256] = a1 + MOMENTUM * b1;
}

// ---------------------------------------------------------------------------
// Scatter normalized updates. One block per write `a`: lanes 0..127 own the
// key row, 128..255 the value row; k-loop inside so q/v load once per block.
// ---------------------------------------------------------------------------
__global__ void __launch_bounds__(256) mw_scatter_kernel(
        const float* __restrict__ q,
        const float* __restrict__ v,
        const float* __restrict__ gate,
        const int* __restrict__ top_idx,
        const float* __restrict__ counts,
        float* __restrict__ outk,
        float* __restrict__ outv) {
    int a = blockIdx.x;                   // 0 .. B-1
    float g = gate[a];
    float w = (g > GATE_THRESH) ? g * UPDATE_RATE : 0.0f;
    if (w == 0.0f) return;                // block-uniform exit
    int t = threadIdx.x;
    int d = t & (DIM - 1);
    bool is_key = (t < DIM);
    float x = is_key ? q[a * DIM + d] : v[a * DIM + d];
    float* base = is_key ? outk : outv;
    float wm = (1.0f - MOMENTUM) * w;
#pragma unroll
    for (int k = 0; k < K_TOP; ++k) {
        int s = top_idx[a * K_TOP + k];
        float cnt = counts[s];
        float denom = (cnt > 0.0f) ? cnt : 1.0f;
        float c = wm / denom;
        atomicAdd(&base[s * DIM + d], c * x);
    }
}

extern "C" void kernel_launch(void* const* d_in, const int* in_sizes, int n_in,
                              void* d_out, int out_size, void* d_ws, size_t ws_size,
                              hipStream_t stream) {
    const float* memory_keys    = (const float*)d_in[0];
    const float* memory_values  = (const float*)d_in[1];
    const float* write_query    = (const float*)d_in[2];
    const float* write_value    = (const float*)d_in[3];
    const float* gate_weights   = (const float*)d_in[4];
    const int*   top_indices    = (const int*)d_in[5];
    const float* key_momentum   = (const float*)d_in[6];
    const float* value_momentum = (const float*)d_in[7];

    float* out  = (float*)d_out;
    float* outk = out;
    float* outv = out + (size_t)N_SLOTS * DIM;

    float* counts = (float*)d_ws;         // 65536 floats = 256 KB

    // 0) zero the counts accumulator (deterministic per call)
    hipMemsetAsync(counts, 0, N_SLOTS * sizeof(float), stream);

    // 1) fused: streaming base pass (block-halved, XCD-swizzled) + counts
    {
        int grid = 8192;                  // 4096 blocks per half, 8 KB each
        mw_base_kernel<<<grid, 256, 0, stream>>>(
            (const f32x4*)memory_keys, (const f32x4*)memory_values,
            (const f32x4*)key_momentum, (const f32x4*)value_momentum,
            (f32x4*)outk, (f32x4*)outv,
            gate_weights, top_indices, counts);
    }

    // 2) scatter normalized updates into the output
    {
        mw_scatter_kernel<<<B_SZ, 256, 0, stream>>>(
            write_query, write_value, gate_weights, top_indices, counts,
            outk, outv);
    }
}